// Round 7
// baseline (4457.142 us; speedup 1.0000x reference)
//
#include <hip/hip_runtime.h>
#include <cstddef>

#define L 16
#define PLANE 256
#define VOL 65536

typedef __attribute__((ext_vector_type(8))) short short8;
typedef __attribute__((ext_vector_type(4))) float f32x4;
typedef __attribute__((ext_vector_type(4))) int i32x4;
typedef unsigned int u32;
typedef unsigned short u16;

__device__ __forceinline__ u16 f2bf(float f) {
    u32 u = __builtin_bit_cast(u32, f);
    return (u16)((u + 0x7FFFu + ((u >> 16) & 1u)) >> 16);
}
__device__ __forceinline__ float bf2f(u16 h) {
    u32 u = ((u32)h) << 16;
    return __builtin_bit_cast(float, u);
}

// DPP lane-shift within 16-lane rows; bound_ctrl + old=0 -> zero fill at row
// edges == SAME-padding for the d4 dimension, for free.
template <int CTRL>
__device__ __forceinline__ int dppmov(int v) {
    return __builtin_amdgcn_update_dpp(0, v, CTRL, 0xf, 0xf, true);
}
template <int CTRL>
__device__ __forceinline__ short8 dpp8(short8 v) {
    i32x4 u = __builtin_bit_cast(i32x4, v), r;
    r[0] = dppmov<CTRL>(u[0]); r[1] = dppmov<CTRL>(u[1]);
    r[2] = dppmov<CTRL>(u[2]); r[3] = dppmov<CTRL>(u[3]);
    return __builtin_bit_cast(short8, r);
}

// ---------------------------------------------------------------------------
// Pack layer0 (IC=2) weights to fp32 [i][tap][o].
// ---------------------------------------------------------------------------
__global__ void pack_w0(const float* __restrict__ k0, float* __restrict__ dst)
{
    int idx = blockIdx.x * 256 + threadIdx.x;   // (i*81 + t)*32 + o
    if (idx >= 2 * 81 * 32) return;
    int o = idx & 31;
    int t = (idx >> 5) % 81;
    int i = idx / (32 * 81);
    dst[idx] = k0[(size_t)(o * 2 + i) * 81 + t];
}

// ---------------------------------------------------------------------------
// Split-pack k1..k4: wpk[layer][tap][{hi,lo}][o][i], 81*2048 u16 per layer.
// ---------------------------------------------------------------------------
__global__ void pack_split(const float* __restrict__ k1, const float* __restrict__ k2,
                           const float* __restrict__ k3, const float* __restrict__ k4,
                           u16* __restrict__ dst)
{
    int idx = blockIdx.x * 256 + threadIdx.x;
    if (idx >= 4 * 81 * 1024) return;
    int layer = idx / (81 * 1024);
    int r = idx % (81 * 1024);
    int t = r / 1024;
    int oi = r % 1024;                  // o*32 + i
    int o = oi >> 5, i = oi & 31;
    const float* src = layer == 0 ? k1 : layer == 1 ? k2 : layer == 2 ? k3 : k4;
    float w = src[(size_t)(o * 32 + i) * 81 + t];
    u16 h = f2bf(w);
    u16 l = f2bf(w - bf2f(h));
    size_t base = ((size_t)layer * 81 + t) * 2048 + oi;
    dst[base] = h;
    dst[base + 1024] = l;
}

// ---------------------------------------------------------------------------
// MFMA conv layer, IC=OC=32, PReLU. NO LDS, NO barriers. Activations in
// split hi/lo buffers, layout [n][d1][d2][pos=d3*16+d4][ch]: each lane's
// A-frag (8 ch at one position) is one contiguous 16B global load (L1/L2-hot;
// plane reuse across dd done in-register via DPP row shifts).
// launch_bounds(256,6): VGPR cap 85 (natural demand 80) -> up to 6 blocks/CU
// so per-tap B-load L2 latency is covered by co-resident waves' MFMA issue.
// ---------------------------------------------------------------------------
__global__ __launch_bounds__(256, 6)
void conv4d_mfma(const u16* __restrict__ xh, const u16* __restrict__ xl,
                 const u16* __restrict__ wl_, const float* __restrict__ slopes,
                 int sidx, u16* __restrict__ yh, u16* __restrict__ yl)
{
    const int blk = blockIdx.x;
    // XCD swizzle: xcd = blk&7 owns d1 rows {2*xcd, 2*xcd+1}, n-major order,
    // so each XCD's live plane set (~2 MB/n) fits its 4 MB L2.
    const int xcd = blk & 7;
    const int s = blk >> 3;
    const int n = s >> 5;
    const int t = s & 31;
    const int d1 = xcd * 2 + (t >> 4);
    const int d2 = t & 15;

    const int lane = threadIdx.x & 63, wv = threadIdx.x >> 6;
    const int l15 = lane & 15, q = lane >> 4;

    f32x4 acc[4][2];
#pragma unroll
    for (int f = 0; f < 4; ++f)
#pragma unroll
        for (int nf = 0; nf < 2; ++nf)
            acc[f][nf] = (f32x4){0.f, 0.f, 0.f, 0.f};

    const size_t nbase = (size_t)n * 256 * 8192;
    const int aoff = l15 * 32 + q * 8;       // within-plane frag offset (dd=1)

#pragma unroll 1
    for (int da = 0; da < 3; ++da) {
        const int a = d1 + da - 1;
        if ((unsigned)a > 15u) continue;     // block-uniform: pad plane = 0
#pragma unroll 1
        for (int db = 0; db < 3; ++db) {
            const int b = d2 + db - 1;
            if ((unsigned)b > 15u) continue;
            const size_t pbase = nbase + (size_t)(a * 16 + b) * 8192;
            const u16* Hp = xh + pbase;
            const u16* Lp = xl + pbase;
            const u16* wt0 = wl_ + (size_t)((da * 3 + db) * 9) * 2048;

            // base A-frags (dd=1, col=l15): rows wv*4-1 .. wv*4+4
            short8 axh[6], axl[6];
#pragma unroll
            for (int r6 = 0; r6 < 6; ++r6) {
                const int d3c = (wv * 4 + r6 - 1) & 15;   // wrap; OOB zeroed below
                axh[r6] = *(const short8*)(Hp + d3c * 512 + aoff);
                axl[r6] = *(const short8*)(Lp + d3c * 512 + aoff);
            }
            if (wv == 0) {          // d3 = -1 pad row (wave-uniform)
                axh[0] = (short8){0,0,0,0,0,0,0,0};
                axl[0] = (short8){0,0,0,0,0,0,0,0};
            } else if (wv == 3) {   // d3 = 16 pad row
                axh[5] = (short8){0,0,0,0,0,0,0,0};
                axl[5] = (short8){0,0,0,0,0,0,0,0};
            }

            // ---- dd = 0 (col l15-1, via row_shr:1), 1 (base), 2 (row_shl:1)
#pragma unroll
            for (int dc = 0; dc < 3; ++dc) {
                const u16* wb = wt0 + (dc * 3 + 0) * 2048;
                short8 wh0 = *(const short8*)(wb + aoff);
                short8 wh1 = *(const short8*)(wb + 512 + aoff);
                short8 wl0 = *(const short8*)(wb + 1024 + aoff);
                short8 wl1 = *(const short8*)(wb + 1536 + aoff);
#pragma unroll
                for (int f = 0; f < 4; ++f) {
                    short8 Ah = dpp8<0x111>(axh[f + dc]);
                    short8 Al = dpp8<0x111>(axl[f + dc]);
                    acc[f][0] = __builtin_amdgcn_mfma_f32_16x16x32_bf16(Ah, wh0, acc[f][0], 0, 0, 0);
                    acc[f][1] = __builtin_amdgcn_mfma_f32_16x16x32_bf16(Ah, wh1, acc[f][1], 0, 0, 0);
                    acc[f][0] = __builtin_amdgcn_mfma_f32_16x16x32_bf16(Ah, wl0, acc[f][0], 0, 0, 0);
                    acc[f][1] = __builtin_amdgcn_mfma_f32_16x16x32_bf16(Ah, wl1, acc[f][1], 0, 0, 0);
                    acc[f][0] = __builtin_amdgcn_mfma_f32_16x16x32_bf16(Al, wh0, acc[f][0], 0, 0, 0);
                    acc[f][1] = __builtin_amdgcn_mfma_f32_16x16x32_bf16(Al, wh1, acc[f][1], 0, 0, 0);
                }
            }
#pragma unroll
            for (int dc = 0; dc < 3; ++dc) {
                const u16* wb = wt0 + (dc * 3 + 1) * 2048;
                short8 wh0 = *(const short8*)(wb + aoff);
                short8 wh1 = *(const short8*)(wb + 512 + aoff);
                short8 wl0 = *(const short8*)(wb + 1024 + aoff);
                short8 wl1 = *(const short8*)(wb + 1536 + aoff);
#pragma unroll
                for (int f = 0; f < 4; ++f) {
                    short8 Ah = axh[f + dc];
                    short8 Al = axl[f + dc];
                    acc[f][0] = __builtin_amdgcn_mfma_f32_16x16x32_bf16(Ah, wh0, acc[f][0], 0, 0, 0);
                    acc[f][1] = __builtin_amdgcn_mfma_f32_16x16x32_bf16(Ah, wh1, acc[f][1], 0, 0, 0);
                    acc[f][0] = __builtin_amdgcn_mfma_f32_16x16x32_bf16(Ah, wl0, acc[f][0], 0, 0, 0);
                    acc[f][1] = __builtin_amdgcn_mfma_f32_16x16x32_bf16(Ah, wl1, acc[f][1], 0, 0, 0);
                    acc[f][0] = __builtin_amdgcn_mfma_f32_16x16x32_bf16(Al, wh0, acc[f][0], 0, 0, 0);
                    acc[f][1] = __builtin_amdgcn_mfma_f32_16x16x32_bf16(Al, wh1, acc[f][1], 0, 0, 0);
                }
            }
#pragma unroll
            for (int dc = 0; dc < 3; ++dc) {
                const u16* wb = wt0 + (dc * 3 + 2) * 2048;
                short8 wh0 = *(const short8*)(wb + aoff);
                short8 wh1 = *(const short8*)(wb + 512 + aoff);
                short8 wl0 = *(const short8*)(wb + 1024 + aoff);
                short8 wl1 = *(const short8*)(wb + 1536 + aoff);
#pragma unroll
                for (int f = 0; f < 4; ++f) {
                    short8 Ah = dpp8<0x101>(axh[f + dc]);
                    short8 Al = dpp8<0x101>(axl[f + dc]);
                    acc[f][0] = __builtin_amdgcn_mfma_f32_16x16x32_bf16(Ah, wh0, acc[f][0], 0, 0, 0);
                    acc[f][1] = __builtin_amdgcn_mfma_f32_16x16x32_bf16(Ah, wh1, acc[f][1], 0, 0, 0);
                    acc[f][0] = __builtin_amdgcn_mfma_f32_16x16x32_bf16(Ah, wl0, acc[f][0], 0, 0, 0);
                    acc[f][1] = __builtin_amdgcn_mfma_f32_16x16x32_bf16(Ah, wl1, acc[f][1], 0, 0, 0);
                    acc[f][0] = __builtin_amdgcn_mfma_f32_16x16x32_bf16(Al, wh0, acc[f][0], 0, 0, 0);
                    acc[f][1] = __builtin_amdgcn_mfma_f32_16x16x32_bf16(Al, wh1, acc[f][1], 0, 0, 0);
                }
            }
        }
    }

    // ---- epilogue: PReLU, split-pack, store to [pos][ch] hi/lo buffers ----
    const float slope = slopes[sidx];
    u16* Hb = yh + ((size_t)(n * 256) + d1 * 16 + d2) * 8192;
    u16* Lb = yl + ((size_t)(n * 256) + d1 * 16 + d2) * 8192;
#pragma unroll
    for (int f = 0; f < 4; ++f) {
#pragma unroll
        for (int nf = 0; nf < 2; ++nf) {
            const int o = nf * 16 + l15;
#pragma unroll
            for (int j = 0; j < 4; ++j) {
                float v = acc[f][nf][j];
                v = v >= 0.f ? v : slope * v;
                u16 h = f2bf(v);
                u16 l = f2bf(v - bf2f(h));
                const int pos = (wv * 4 + f) * 16 + q * 4 + j;
                Hb[pos * 32 + o] = h;
                Lb[pos * 32 + o] = l;
            }
        }
    }
}

// ---------------------------------------------------------------------------
// Layer 0: IC=2, fp32 math, PReLU; original x layout in, split hi/lo out.
// ---------------------------------------------------------------------------
__global__ __launch_bounds__(256, 4)
void conv4d_c2(const float* __restrict__ x, const float* __restrict__ wp,
               const float* __restrict__ slopes,
               u16* __restrict__ yh, u16* __restrict__ yl)
{
    const int blk = blockIdx.x;
    const int d2 = blk & 15, d1 = (blk >> 4) & 15, n = blk >> 8;
    const int tid = threadIdx.x;
    const int c = tid >> 4, d = tid & 15;

    __shared__ float xs[3][3][18][18];
    float* xsf = &xs[0][0][0][0];
    for (int idx = tid; idx < 3 * 3 * 18 * 18; idx += 256) xsf[idx] = 0.0f;

    float acc[32];
#pragma unroll
    for (int o = 0; o < 32; ++o) acc[o] = 0.0f;

    for (int i = 0; i < 2; ++i) {
#pragma unroll
        for (int da = 0; da < 3; ++da) {
            const int a = d1 + da - 1;
#pragma unroll
            for (int db = 0; db < 3; ++db) {
                const int b = d2 + db - 1;
                float v = 0.0f;
                if (a >= 0 && a < L && b >= 0 && b < L)
                    v = x[(((size_t)(n * 2 + i) * L + a) * L + b) * PLANE + c * L + d];
                xs[da][db][c + 1][d + 1] = v;
            }
        }
        __syncthreads();

        const float* wpi = wp + (size_t)i * 81 * 32;
#pragma unroll 1
        for (int da = 0; da < 3; ++da) {
#pragma unroll 1
            for (int db = 0; db < 3; ++db) {
                float xv[3][3];
#pragma unroll
                for (int dc = 0; dc < 3; ++dc)
#pragma unroll
                    for (int dd = 0; dd < 3; ++dd)
                        xv[dc][dd] = xs[da][db][c + dc][d + dd];

                const float* wt = wpi + (da * 3 + db) * 9 * 32;
#pragma unroll
                for (int dc = 0; dc < 3; ++dc) {
#pragma unroll
                    for (int dd = 0; dd < 3; ++dd) {
                        const float* wr = wt + (dc * 3 + dd) * 32;
#pragma unroll
                        for (int o = 0; o < 32; ++o)
                            acc[o] = fmaf(xv[dc][dd], wr[o], acc[o]);
                    }
                }
            }
        }
        __syncthreads();
    }

    const float slope = slopes[0];
    u16* Hb = yh + ((size_t)(n * 256) + d1 * 16 + d2) * 8192 + (size_t)tid * 32;
    u16* Lb = yl + ((size_t)(n * 256) + d1 * 16 + d2) * 8192 + (size_t)tid * 32;
    short8 hs[4], ls[4];
#pragma unroll
    for (int k = 0; k < 4; ++k)
#pragma unroll
        for (int j = 0; j < 8; ++j) {
            float v = acc[k * 8 + j];
            v = v >= 0.f ? v : slope * v;
            u16 h = f2bf(v);
            u16 l = f2bf(v - bf2f(h));
            hs[k][j] = (short)h;
            ls[k][j] = (short)l;
        }
#pragma unroll
    for (int k = 0; k < 4; ++k) {
        *(short8*)(Hb + k * 8) = hs[k];
        *(short8*)(Lb + k * 8) = ls[k];
    }
}

// ---------------------------------------------------------------------------
// Final layer: IC=32, OC=2, no PReLU. hi/lo [pos][ch] input, LDS plane
// staging with register prefetch; k5 weights via wave-uniform s_loads.
// ---------------------------------------------------------------------------
__global__ __launch_bounds__(256, 4)
void conv4d_out(const u16* __restrict__ xh, const u16* __restrict__ xl,
                const float* __restrict__ k5, float* __restrict__ out)
{
    const int blk = blockIdx.x;
    const int d2 = blk & 15, d1 = (blk >> 4) & 15, n = blk >> 8;
    const int tid = threadIdx.x;
    const int c = tid >> 4, d = tid & 15;

    __shared__ float xs2[32 * 288];   // [ch][18*16]
    for (int i = tid; i < 1024; i += 256) {   // zero rows 0,17 per channel
        int ch = i >> 5, rem = i & 31;
        int rr = (rem >> 4) ? 17 : 0;
        xs2[ch * 288 + rr * 16 + (rem & 15)] = 0.0f;
    }

    const size_t nbase = (size_t)n * 256 * 8192;

    short8 rh[4], rl[4];
    {
        int a = d1 - 1, b = d2 - 1;
        if (a >= 0 && b >= 0) {
            const u16* Hp = xh + nbase + (size_t)(a * 16 + b) * 8192 + (size_t)tid * 32;
            const u16* Lp = xl + nbase + (size_t)(a * 16 + b) * 8192 + (size_t)tid * 32;
#pragma unroll
            for (int k = 0; k < 4; ++k) { rh[k] = *(const short8*)(Hp + k * 8);
                                          rl[k] = *(const short8*)(Lp + k * 8); }
        } else {
#pragma unroll
            for (int k = 0; k < 4; ++k) { rh[k] = (short8){0,0,0,0,0,0,0,0};
                                          rl[k] = (short8){0,0,0,0,0,0,0,0}; }
        }
    }

    float acc0 = 0.0f, acc1 = 0.0f;
    const int wpos = (c + 1) * 16 + d;

#pragma unroll 1
    for (int p = 0; p < 9; ++p) {
        __syncthreads();
#pragma unroll
        for (int k = 0; k < 4; ++k)
#pragma unroll
            for (int j = 0; j < 8; ++j)
                xs2[(k * 8 + j) * 288 + wpos] =
                    bf2f((u16)rh[k][j]) + bf2f((u16)rl[k][j]);
        __syncthreads();
        if (p < 8) {
            int pn = p + 1;
            int da = (pn * 11) >> 5, db = pn - da * 3;
            int a = d1 + da - 1, b = d2 + db - 1;
            if (a >= 0 && a < 16 && b >= 0 && b < 16) {
                const u16* Hp = xh + nbase + (size_t)(a * 16 + b) * 8192 + (size_t)tid * 32;
                const u16* Lp = xl + nbase + (size_t)(a * 16 + b) * 8192 + (size_t)tid * 32;
#pragma unroll
                for (int k = 0; k < 4; ++k) { rh[k] = *(const short8*)(Hp + k * 8);
                                              rl[k] = *(const short8*)(Lp + k * 8); }
            } else {
#pragma unroll
                for (int k = 0; k < 4; ++k) { rh[k] = (short8){0,0,0,0,0,0,0,0};
                                              rl[k] = (short8){0,0,0,0,0,0,0,0}; }
            }
        }

#pragma unroll 1
        for (int dc = 0; dc < 3; ++dc) {
#pragma unroll 1
            for (int dd = 0; dd < 3; ++dd) {
                const int ce = d + dd - 1;
                if ((unsigned)ce < 16u) {         // edge col = pad = 0: skip
                    const int tap = p * 9 + dc * 3 + dd;
                    const int rpos = (c + dc) * 16 + ce;
#pragma unroll
                    for (int i = 0; i < 32; ++i) {
                        const float v = xs2[i * 288 + rpos];
                        acc0 = fmaf(v, k5[i * 81 + tap], acc0);
                        acc1 = fmaf(v, k5[(32 + i) * 81 + tap], acc1);
                    }
                }
            }
        }
    }

    const size_t base = (size_t)(n * 2) * VOL + (size_t)(d1 * 16 + d2) * 256 + tid;
    out[base] = acc0;
    out[base + VOL] = acc1;
}

extern "C" void kernel_launch(void* const* d_in, const int* in_sizes, int n_in,
                              void* d_out, int out_size, void* d_ws, size_t ws_size,
                              hipStream_t stream)
{
    (void)in_sizes; (void)n_in; (void)out_size; (void)ws_size;
    const float* x      = (const float*)d_in[0];
    const float* k0     = (const float*)d_in[1];
    const float* k1     = (const float*)d_in[2];
    const float* k2     = (const float*)d_in[3];
    const float* k3     = (const float*)d_in[4];
    const float* k4     = (const float*)d_in[5];
    const float* k5     = (const float*)d_in[6];
    const float* slopes = (const float*)d_in[7];
    float* outp = (float*)d_out;

    // Split hi/lo activation buffers in d_ws: 4 x 32 MB = 128 MB.
    u16* b0h = (u16*)d_ws;
    u16* b0l = b0h + (size_t)2048 * 8192;
    u16* b1h = b0l + (size_t)2048 * 8192;
    u16* b1l = b1h + (size_t)2048 * 8192;

    // Scratch weights in d_out (overwritten by the final conv):
    u16* wpk = (u16*)d_out;                 // 663552 u16 = 1.33 MB
    float* wp0 = outp + 331776;             // 5184 fp32 after that

    pack_split<<<dim3(1296), 256, 0, stream>>>(k1, k2, k3, k4, wpk);
    pack_w0<<<dim3(21), 256, 0, stream>>>(k0, wp0);

    const dim3 grid(8 * L * L);
    const dim3 block(256);

    conv4d_c2<<<grid, block, 0, stream>>>(x, wp0, slopes, b0h, b0l);
    conv4d_mfma<<<grid, block, 0, stream>>>(b0h, b0l, wpk + (size_t)0 * 81 * 2048, slopes, 1, b1h, b1l);
    conv4d_mfma<<<grid, block, 0, stream>>>(b1h, b1l, wpk + (size_t)1 * 81 * 2048, slopes, 2, b0h, b0l);
    conv4d_mfma<<<grid, block, 0, stream>>>(b0h, b0l, wpk + (size_t)2 * 81 * 2048, slopes, 3, b1h, b1l);
    conv4d_mfma<<<grid, block, 0, stream>>>(b1h, b1l, wpk + (size_t)3 * 81 * 2048, slopes, 4, b0h, b0l);
    conv4d_out<<<grid, block, 0, stream>>>(b0h, b0l, k5, outp);
}

// Round 8
// 1168.721 us; speedup vs baseline: 3.8137x; 3.8137x over previous
//
#include <hip/hip_runtime.h>
#include <cstddef>

#define L 16
#define PLANE 256
#define VOL 65536

typedef __attribute__((ext_vector_type(8))) short short8;
typedef __attribute__((ext_vector_type(4))) float f32x4;
typedef __attribute__((ext_vector_type(4))) int i32x4;
typedef unsigned int u32;
typedef unsigned short u16;

__device__ __forceinline__ u16 f2bf(float f) {
    u32 u = __builtin_bit_cast(u32, f);
    return (u16)((u + 0x7FFFu + ((u >> 16) & 1u)) >> 16);
}
__device__ __forceinline__ float bf2f(u16 h) {
    u32 u = ((u32)h) << 16;
    return __builtin_bit_cast(float, u);
}

// DPP lane-shift within 16-lane rows; bound_ctrl + old=0 -> zero fill at row
// edges == SAME-padding for the d4 dimension, for free.
template <int CTRL>
__device__ __forceinline__ int dppmov(int v) {
    return __builtin_amdgcn_update_dpp(0, v, CTRL, 0xf, 0xf, true);
}
template <int CTRL>
__device__ __forceinline__ short8 dpp8(short8 v) {
    i32x4 u = __builtin_bit_cast(i32x4, v), r;
    r[0] = dppmov<CTRL>(u[0]); r[1] = dppmov<CTRL>(u[1]);
    r[2] = dppmov<CTRL>(u[2]); r[3] = dppmov<CTRL>(u[3]);
    return __builtin_bit_cast(short8, r);
}

// ---------------------------------------------------------------------------
// Pack layer0 (IC=2) weights to fp32 [i][tap][o].
// ---------------------------------------------------------------------------
__global__ void pack_w0(const float* __restrict__ k0, float* __restrict__ dst)
{
    int idx = blockIdx.x * 256 + threadIdx.x;   // (i*81 + t)*32 + o
    if (idx >= 2 * 81 * 32) return;
    int o = idx & 31;
    int t = (idx >> 5) % 81;
    int i = idx / (32 * 81);
    dst[idx] = k0[(size_t)(o * 2 + i) * 81 + t];
}

// ---------------------------------------------------------------------------
// Split-pack k1..k4: wpk[layer][tap][{hi,lo}][o][i], 81*2048 u16 per layer.
// ---------------------------------------------------------------------------
__global__ void pack_split(const float* __restrict__ k1, const float* __restrict__ k2,
                           const float* __restrict__ k3, const float* __restrict__ k4,
                           u16* __restrict__ dst)
{
    int idx = blockIdx.x * 256 + threadIdx.x;
    if (idx >= 4 * 81 * 1024) return;
    int layer = idx / (81 * 1024);
    int r = idx % (81 * 1024);
    int t = r / 1024;
    int oi = r % 1024;                  // o*32 + i
    int o = oi >> 5, i = oi & 31;
    const float* src = layer == 0 ? k1 : layer == 1 ? k2 : layer == 2 ? k3 : k4;
    float w = src[(size_t)(o * 32 + i) * 81 + t];
    u16 h = f2bf(w);
    u16 l = f2bf(w - bf2f(h));
    size_t base = ((size_t)layer * 81 + t) * 2048 + oi;
    dst[base] = h;
    dst[base + 1024] = l;
}

// ---------------------------------------------------------------------------
// MFMA conv layer, IC=OC=32, PReLU. NO LDS, NO barriers. Activations in
// split hi/lo buffers, layout [n][d1][d2][pos=d3*16+d4][ch]. Per plane:
// 12 A-frag b128 loads, then 9 taps with ONE-TAP-AHEAD B double-buffer so
// tap t's 24 MFMA overlap tap t+1's 4 L2 loads (fine-grained vmcnt).
// Register budget ~128 unified (32 acc + 48 A + 32 B dbuf + addr) = the
// 4-waves/SIMD boundary; lb(256,3) so the compiler never force-spills.
// ---------------------------------------------------------------------------
__global__ __launch_bounds__(256, 3)
void conv4d_mfma(const u16* __restrict__ xh, const u16* __restrict__ xl,
                 const u16* __restrict__ wl_, const float* __restrict__ slopes,
                 int sidx, u16* __restrict__ yh, u16* __restrict__ yl)
{
    const int blk = blockIdx.x;
    // XCD swizzle: xcd = blk&7 owns d1 rows {2*xcd, 2*xcd+1}, n-major order.
    const int xcd = blk & 7;
    const int s = blk >> 3;
    const int n = s >> 5;
    const int t_ = s & 31;
    const int d1 = xcd * 2 + (t_ >> 4);
    const int d2 = t_ & 15;

    const int lane = threadIdx.x & 63, wv = threadIdx.x >> 6;
    const int l15 = lane & 15, q = lane >> 4;

    f32x4 acc[4][2];
#pragma unroll
    for (int f = 0; f < 4; ++f)
#pragma unroll
        for (int nf = 0; nf < 2; ++nf)
            acc[f][nf] = (f32x4){0.f, 0.f, 0.f, 0.f};

    const size_t nbase = (size_t)n * 256 * 8192;
    const int aoff = l15 * 32 + q * 8;       // within-plane frag offset (dd=1)

#pragma unroll 1
    for (int da = 0; da < 3; ++da) {
        const int a = d1 + da - 1;
        if ((unsigned)a > 15u) continue;     // block-uniform: pad plane = 0
#pragma unroll 1
        for (int db = 0; db < 3; ++db) {
            const int b = d2 + db - 1;
            if ((unsigned)b > 15u) continue;
            const size_t pbase = nbase + (size_t)(a * 16 + b) * 8192;
            const u16* Hp = xh + pbase;
            const u16* Lp = xl + pbase;
            const u16* wt0 = wl_ + (size_t)((da * 3 + db) * 9) * 2048;

            // base A-frags (dd=1, col=l15): rows wv*4-1 .. wv*4+4
            short8 axh[6], axl[6];
#pragma unroll
            for (int r6 = 0; r6 < 6; ++r6) {
                const int d3c = (wv * 4 + r6 - 1) & 15;   // wrap; OOB zeroed below
                axh[r6] = *(const short8*)(Hp + d3c * 512 + aoff);
                axl[r6] = *(const short8*)(Lp + d3c * 512 + aoff);
            }
            if (wv == 0) {          // d3 = -1 pad row (wave-uniform)
                axh[0] = (short8){0,0,0,0,0,0,0,0};
                axl[0] = (short8){0,0,0,0,0,0,0,0};
            } else if (wv == 3) {   // d3 = 16 pad row
                axh[5] = (short8){0,0,0,0,0,0,0,0};
                axl[5] = (short8){0,0,0,0,0,0,0,0};
            }

            // ---- 9 taps, flattened (dd major, dc minor), B double-buffered.
            // Weight tap index is (dc*3+dd).
            short8 Bh0[2], Bh1[2], Bl0[2], Bl1[2];
            {   // preload tap 0 (dd=0, dc=0)
                const u16* wb = wt0;          // (0*3+0)*2048
                Bh0[0] = *(const short8*)(wb + aoff);
                Bh1[0] = *(const short8*)(wb + 512 + aoff);
                Bl0[0] = *(const short8*)(wb + 1024 + aoff);
                Bl1[0] = *(const short8*)(wb + 1536 + aoff);
            }
#pragma unroll
            for (int t = 0; t < 9; ++t) {
                const int dd = t / 3, dc = t % 3;
                const int cur = t & 1;
                if (t < 8) {                  // issue next tap's B loads NOW
                    const int tn = t + 1;
                    const int ddn = tn / 3, dcn = tn % 3;
                    const u16* wb = wt0 + (dcn * 3 + ddn) * 2048;
                    const int nxt = tn & 1;
                    Bh0[nxt] = *(const short8*)(wb + aoff);
                    Bh1[nxt] = *(const short8*)(wb + 512 + aoff);
                    Bl0[nxt] = *(const short8*)(wb + 1024 + aoff);
                    Bl1[nxt] = *(const short8*)(wb + 1536 + aoff);
                }
#pragma unroll
                for (int f = 0; f < 4; ++f) {
                    short8 Ah, Al;
                    if (dd == 0)      { Ah = dpp8<0x111>(axh[f + dc]); Al = dpp8<0x111>(axl[f + dc]); }
                    else if (dd == 1) { Ah = axh[f + dc];              Al = axl[f + dc]; }
                    else              { Ah = dpp8<0x101>(axh[f + dc]); Al = dpp8<0x101>(axl[f + dc]); }
                    acc[f][0] = __builtin_amdgcn_mfma_f32_16x16x32_bf16(Ah, Bh0[cur], acc[f][0], 0, 0, 0);
                    acc[f][1] = __builtin_amdgcn_mfma_f32_16x16x32_bf16(Ah, Bh1[cur], acc[f][1], 0, 0, 0);
                    acc[f][0] = __builtin_amdgcn_mfma_f32_16x16x32_bf16(Ah, Bl0[cur], acc[f][0], 0, 0, 0);
                    acc[f][1] = __builtin_amdgcn_mfma_f32_16x16x32_bf16(Ah, Bl1[cur], acc[f][1], 0, 0, 0);
                    acc[f][0] = __builtin_amdgcn_mfma_f32_16x16x32_bf16(Al, Bh0[cur], acc[f][0], 0, 0, 0);
                    acc[f][1] = __builtin_amdgcn_mfma_f32_16x16x32_bf16(Al, Bh1[cur], acc[f][1], 0, 0, 0);
                }
            }
        }
    }

    // ---- epilogue: PReLU, split-pack, store to [pos][ch] hi/lo buffers ----
    const float slope = slopes[sidx];
    u16* Hb = yh + ((size_t)(n * 256) + d1 * 16 + d2) * 8192;
    u16* Lb = yl + ((size_t)(n * 256) + d1 * 16 + d2) * 8192;
#pragma unroll
    for (int f = 0; f < 4; ++f) {
#pragma unroll
        for (int nf = 0; nf < 2; ++nf) {
            const int o = nf * 16 + l15;
#pragma unroll
            for (int j = 0; j < 4; ++j) {
                float v = acc[f][nf][j];
                v = v >= 0.f ? v : slope * v;
                u16 h = f2bf(v);
                u16 l = f2bf(v - bf2f(h));
                const int pos = (wv * 4 + f) * 16 + q * 4 + j;
                Hb[pos * 32 + o] = h;
                Lb[pos * 32 + o] = l;
            }
        }
    }
}

// ---------------------------------------------------------------------------
// Layer 0: IC=2, fp32 math, PReLU; original x layout in, split hi/lo out.
// ---------------------------------------------------------------------------
__global__ __launch_bounds__(256, 4)
void conv4d_c2(const float* __restrict__ x, const float* __restrict__ wp,
               const float* __restrict__ slopes,
               u16* __restrict__ yh, u16* __restrict__ yl)
{
    const int blk = blockIdx.x;
    const int d2 = blk & 15, d1 = (blk >> 4) & 15, n = blk >> 8;
    const int tid = threadIdx.x;
    const int c = tid >> 4, d = tid & 15;

    __shared__ float xs[3][3][18][18];
    float* xsf = &xs[0][0][0][0];
    for (int idx = tid; idx < 3 * 3 * 18 * 18; idx += 256) xsf[idx] = 0.0f;

    float acc[32];
#pragma unroll
    for (int o = 0; o < 32; ++o) acc[o] = 0.0f;

    for (int i = 0; i < 2; ++i) {
#pragma unroll
        for (int da = 0; da < 3; ++da) {
            const int a = d1 + da - 1;
#pragma unroll
            for (int db = 0; db < 3; ++db) {
                const int b = d2 + db - 1;
                float v = 0.0f;
                if (a >= 0 && a < L && b >= 0 && b < L)
                    v = x[(((size_t)(n * 2 + i) * L + a) * L + b) * PLANE + c * L + d];
                xs[da][db][c + 1][d + 1] = v;
            }
        }
        __syncthreads();

        const float* wpi = wp + (size_t)i * 81 * 32;
#pragma unroll 1
        for (int da = 0; da < 3; ++da) {
#pragma unroll 1
            for (int db = 0; db < 3; ++db) {
                float xv[3][3];
#pragma unroll
                for (int dc = 0; dc < 3; ++dc)
#pragma unroll
                    for (int dd = 0; dd < 3; ++dd)
                        xv[dc][dd] = xs[da][db][c + dc][d + dd];

                const float* wt = wpi + (da * 3 + db) * 9 * 32;
#pragma unroll
                for (int dc = 0; dc < 3; ++dc) {
#pragma unroll
                    for (int dd = 0; dd < 3; ++dd) {
                        const float* wr = wt + (dc * 3 + dd) * 32;
#pragma unroll
                        for (int o = 0; o < 32; ++o)
                            acc[o] = fmaf(xv[dc][dd], wr[o], acc[o]);
                    }
                }
            }
        }
        __syncthreads();
    }

    const float slope = slopes[0];
    u16* Hb = yh + ((size_t)(n * 256) + d1 * 16 + d2) * 8192 + (size_t)tid * 32;
    u16* Lb = yl + ((size_t)(n * 256) + d1 * 16 + d2) * 8192 + (size_t)tid * 32;
    short8 hs[4], ls[4];
#pragma unroll
    for (int k = 0; k < 4; ++k)
#pragma unroll
        for (int j = 0; j < 8; ++j) {
            float v = acc[k * 8 + j];
            v = v >= 0.f ? v : slope * v;
            u16 h = f2bf(v);
            u16 l = f2bf(v - bf2f(h));
            hs[k][j] = (short)h;
            ls[k][j] = (short)l;
        }
#pragma unroll
    for (int k = 0; k < 4; ++k) {
        *(short8*)(Hb + k * 8) = hs[k];
        *(short8*)(Lb + k * 8) = ls[k];
    }
}

// ---------------------------------------------------------------------------
// Final layer: IC=32, OC=2, no PReLU. hi/lo [pos][ch] input, LDS plane
// staging with register prefetch; k5 weights via wave-uniform s_loads.
// ---------------------------------------------------------------------------
__global__ __launch_bounds__(256, 4)
void conv4d_out(const u16* __restrict__ xh, const u16* __restrict__ xl,
                const float* __restrict__ k5, float* __restrict__ out)
{
    const int blk = blockIdx.x;
    const int d2 = blk & 15, d1 = (blk >> 4) & 15, n = blk >> 8;
    const int tid = threadIdx.x;
    const int c = tid >> 4, d = tid & 15;

    __shared__ float xs2[32 * 288];   // [ch][18*16]
    for (int i = tid; i < 1024; i += 256) {   // zero rows 0,17 per channel
        int ch = i >> 5, rem = i & 31;
        int rr = (rem >> 4) ? 17 : 0;
        xs2[ch * 288 + rr * 16 + (rem & 15)] = 0.0f;
    }

    const size_t nbase = (size_t)n * 256 * 8192;

    short8 rh[4], rl[4];
    {
        int a = d1 - 1, b = d2 - 1;
        if (a >= 0 && b >= 0) {
            const u16* Hp = xh + nbase + (size_t)(a * 16 + b) * 8192 + (size_t)tid * 32;
            const u16* Lp = xl + nbase + (size_t)(a * 16 + b) * 8192 + (size_t)tid * 32;
#pragma unroll
            for (int k = 0; k < 4; ++k) { rh[k] = *(const short8*)(Hp + k * 8);
                                          rl[k] = *(const short8*)(Lp + k * 8); }
        } else {
#pragma unroll
            for (int k = 0; k < 4; ++k) { rh[k] = (short8){0,0,0,0,0,0,0,0};
                                          rl[k] = (short8){0,0,0,0,0,0,0,0}; }
        }
    }

    float acc0 = 0.0f, acc1 = 0.0f;
    const int wpos = (c + 1) * 16 + d;

#pragma unroll 1
    for (int p = 0; p < 9; ++p) {
        __syncthreads();
#pragma unroll
        for (int k = 0; k < 4; ++k)
#pragma unroll
            for (int j = 0; j < 8; ++j)
                xs2[(k * 8 + j) * 288 + wpos] =
                    bf2f((u16)rh[k][j]) + bf2f((u16)rl[k][j]);
        __syncthreads();
        if (p < 8) {
            int pn = p + 1;
            int da = (pn * 11) >> 5, db = pn - da * 3;
            int a = d1 + da - 1, b = d2 + db - 1;
            if (a >= 0 && a < 16 && b >= 0 && b < 16) {
                const u16* Hp = xh + nbase + (size_t)(a * 16 + b) * 8192 + (size_t)tid * 32;
                const u16* Lp = xl + nbase + (size_t)(a * 16 + b) * 8192 + (size_t)tid * 32;
#pragma unroll
                for (int k = 0; k < 4; ++k) { rh[k] = *(const short8*)(Hp + k * 8);
                                              rl[k] = *(const short8*)(Lp + k * 8); }
            } else {
#pragma unroll
                for (int k = 0; k < 4; ++k) { rh[k] = (short8){0,0,0,0,0,0,0,0};
                                              rl[k] = (short8){0,0,0,0,0,0,0,0}; }
            }
        }

#pragma unroll 1
        for (int dc = 0; dc < 3; ++dc) {
#pragma unroll 1
            for (int dd = 0; dd < 3; ++dd) {
                const int ce = d + dd - 1;
                if ((unsigned)ce < 16u) {         // edge col = pad = 0: skip
                    const int tap = p * 9 + dc * 3 + dd;
                    const int rpos = (c + dc) * 16 + ce;
#pragma unroll
                    for (int i = 0; i < 32; ++i) {
                        const float v = xs2[i * 288 + rpos];
                        acc0 = fmaf(v, k5[i * 81 + tap], acc0);
                        acc1 = fmaf(v, k5[(32 + i) * 81 + tap], acc1);
                    }
                }
            }
        }
    }

    const size_t base = (size_t)(n * 2) * VOL + (size_t)(d1 * 16 + d2) * 256 + tid;
    out[base] = acc0;
    out[base + VOL] = acc1;
}

extern "C" void kernel_launch(void* const* d_in, const int* in_sizes, int n_in,
                              void* d_out, int out_size, void* d_ws, size_t ws_size,
                              hipStream_t stream)
{
    (void)in_sizes; (void)n_in; (void)out_size; (void)ws_size;
    const float* x      = (const float*)d_in[0];
    const float* k0     = (const float*)d_in[1];
    const float* k1     = (const float*)d_in[2];
    const float* k2     = (const float*)d_in[3];
    const float* k3     = (const float*)d_in[4];
    const float* k4     = (const float*)d_in[5];
    const float* k5     = (const float*)d_in[6];
    const float* slopes = (const float*)d_in[7];
    float* outp = (float*)d_out;

    // Split hi/lo activation buffers in d_ws: 4 x 32 MB = 128 MB.
    u16* b0h = (u16*)d_ws;
    u16* b0l = b0h + (size_t)2048 * 8192;
    u16* b1h = b0l + (size_t)2048 * 8192;
    u16* b1l = b1h + (size_t)2048 * 8192;

    // Scratch weights in d_out (overwritten by the final conv):
    u16* wpk = (u16*)d_out;                 // 663552 u16 = 1.33 MB
    float* wp0 = outp + 331776;             // 5184 fp32 after that

    pack_split<<<dim3(1296), 256, 0, stream>>>(k1, k2, k3, k4, wpk);
    pack_w0<<<dim3(21), 256, 0, stream>>>(k0, wp0);

    const dim3 grid(8 * L * L);
    const dim3 block(256);

    conv4d_c2<<<grid, block, 0, stream>>>(x, wp0, slopes, b0h, b0l);
    conv4d_mfma<<<grid, block, 0, stream>>>(b0h, b0l, wpk + (size_t)0 * 81 * 2048, slopes, 1, b1h, b1l);
    conv4d_mfma<<<grid, block, 0, stream>>>(b1h, b1l, wpk + (size_t)1 * 81 * 2048, slopes, 2, b0h, b0l);
    conv4d_mfma<<<grid, block, 0, stream>>>(b0h, b0l, wpk + (size_t)2 * 81 * 2048, slopes, 3, b1h, b1l);
    conv4d_mfma<<<grid, block, 0, stream>>>(b1h, b1l, wpk + (size_t)3 * 81 * 2048, slopes, 4, b0h, b0l);
    conv4d_out<<<grid, block, 0, stream>>>(b0h, b0l, k5, outp);
}

// Round 9
// 968.263 us; speedup vs baseline: 4.6032x; 1.2070x over previous
//
#include <hip/hip_runtime.h>
#include <cstddef>

#define L 16
#define PLANE 256
#define VOL 65536

typedef __attribute__((ext_vector_type(8))) short short8;
typedef __attribute__((ext_vector_type(8))) _Float16 half8;
typedef __attribute__((ext_vector_type(4))) float f32x4;
typedef __attribute__((ext_vector_type(4))) int i32x4;
typedef unsigned int u32;
typedef unsigned short u16;

__device__ __forceinline__ u16 f2h_bits(float f) {
    _Float16 h = (_Float16)f;             // RTN
    return __builtin_bit_cast(u16, h);
}
__device__ __forceinline__ float h2f(u16 b) {
    return (float)__builtin_bit_cast(_Float16, b);
}

// DPP lane-shift within 16-lane rows; bound_ctrl + old=0 -> zero fill at row
// edges == SAME-padding for the d4 dimension, for free.
template <int CTRL>
__device__ __forceinline__ int dppmov(int v) {
    return __builtin_amdgcn_update_dpp(0, v, CTRL, 0xf, 0xf, true);
}
template <int CTRL>
__device__ __forceinline__ half8 dpp8(half8 v) {
    i32x4 u = __builtin_bit_cast(i32x4, v), r;
    r[0] = dppmov<CTRL>(u[0]); r[1] = dppmov<CTRL>(u[1]);
    r[2] = dppmov<CTRL>(u[2]); r[3] = dppmov<CTRL>(u[3]);
    return __builtin_bit_cast(half8, r);
}

// ---------------------------------------------------------------------------
// Pack layer0 (IC=2) weights to fp32 [i][tap][o].
// ---------------------------------------------------------------------------
__global__ void pack_w0(const float* __restrict__ k0, float* __restrict__ dst)
{
    int idx = blockIdx.x * 256 + threadIdx.x;   // (i*81 + t)*32 + o
    if (idx >= 2 * 81 * 32) return;
    int o = idx & 31;
    int t = (idx >> 5) % 81;
    int i = idx / (32 * 81);
    dst[idx] = k0[(size_t)(o * 2 + i) * 81 + t];
}

// ---------------------------------------------------------------------------
// Split-pack k1..k4 to fp16 hi/lo: wpk[layer][tap][{wh,wl}][o][i].
// wh = f16(w), wl = f16(w - wh): wh+wl reconstructs w to ~21 mantissa bits.
// Per layer: 81*2048 u16.
// ---------------------------------------------------------------------------
__global__ void pack_half(const float* __restrict__ k1, const float* __restrict__ k2,
                          const float* __restrict__ k3, const float* __restrict__ k4,
                          u16* __restrict__ dst)
{
    int idx = blockIdx.x * 256 + threadIdx.x;
    if (idx >= 4 * 81 * 1024) return;
    int layer = idx / (81 * 1024);
    int r = idx % (81 * 1024);
    int t = r / 1024;
    int oi = r % 1024;                  // o*32 + i
    int o = oi >> 5, i = oi & 31;
    const float* src = layer == 0 ? k1 : layer == 1 ? k2 : layer == 2 ? k3 : k4;
    float w = src[(size_t)(o * 32 + i) * 81 + t];
    _Float16 wh = (_Float16)w;
    _Float16 wl = (_Float16)(w - (float)wh);
    size_t base = ((size_t)layer * 81 + t) * 2048 + oi;
    dst[base] = __builtin_bit_cast(u16, wh);
    dst[base + 1024] = __builtin_bit_cast(u16, wl);
}

// ---------------------------------------------------------------------------
// MFMA conv layer, IC=OC=32, PReLU. fp16 2-pass: activations fp16 (single
// buffer, [n][d1][d2][pos=d3*16+d4][ch]), weights fp16 hi+lo (exact to 21
// bits). Per tap: 16 x mfma_f32_16x16x32_f16 (4 M-frags x 2 N-frags x 2
// weight passes). NO LDS, NO barriers; d4-shift via DPP row shifts
// (bound_ctrl zero-fill = SAME padding); one-tap-ahead B double-buffer.
// ---------------------------------------------------------------------------
__global__ __launch_bounds__(256, 3)
void conv4d_mfma(const u16* __restrict__ xh, const u16* __restrict__ wl_,
                 const float* __restrict__ slopes, int sidx, u16* __restrict__ yh)
{
    const int blk = blockIdx.x;
    // XCD swizzle: xcd = blk&7 owns d1 rows {2*xcd, 2*xcd+1}, n-major order.
    const int xcd = blk & 7;
    const int s = blk >> 3;
    const int n = s >> 5;
    const int t_ = s & 31;
    const int d1 = xcd * 2 + (t_ >> 4);
    const int d2 = t_ & 15;

    const int lane = threadIdx.x & 63, wv = threadIdx.x >> 6;
    const int l15 = lane & 15, q = lane >> 4;

    f32x4 acc[4][2];
#pragma unroll
    for (int f = 0; f < 4; ++f)
#pragma unroll
        for (int nf = 0; nf < 2; ++nf)
            acc[f][nf] = (f32x4){0.f, 0.f, 0.f, 0.f};

    const size_t nbase = (size_t)n * 256 * 8192;
    const int aoff = l15 * 32 + q * 8;       // within-plane frag offset (dd=1)

#pragma unroll 1
    for (int da = 0; da < 3; ++da) {
        const int a = d1 + da - 1;
        if ((unsigned)a > 15u) continue;     // block-uniform: pad plane = 0
#pragma unroll 1
        for (int db = 0; db < 3; ++db) {
            const int b = d2 + db - 1;
            if ((unsigned)b > 15u) continue;
            const size_t pbase = nbase + (size_t)(a * 16 + b) * 8192;
            const u16* Hp = xh + pbase;
            const u16* wt0 = wl_ + (size_t)((da * 3 + db) * 9) * 2048;

            // base A-frags (dd=1, col=l15): rows wv*4-1 .. wv*4+4
            half8 ax[6];
#pragma unroll
            for (int r6 = 0; r6 < 6; ++r6) {
                const int d3c = (wv * 4 + r6 - 1) & 15;   // wrap; OOB zeroed below
                ax[r6] = *(const half8*)(Hp + d3c * 512 + aoff);
            }
            if (wv == 0)      ax[0] = (half8)(_Float16)0;  // d3 = -1 pad row
            else if (wv == 3) ax[5] = (half8)(_Float16)0;  // d3 = 16 pad row

            // ---- 9 taps, flattened (dd major, dc minor), B double-buffered.
            half8 Bh0[2], Bh1[2], Bl0[2], Bl1[2];
            {   // preload tap 0 (dd=0, dc=0)
                const u16* wb = wt0;
                Bh0[0] = *(const half8*)(wb + aoff);
                Bh1[0] = *(const half8*)(wb + 512 + aoff);
                Bl0[0] = *(const half8*)(wb + 1024 + aoff);
                Bl1[0] = *(const half8*)(wb + 1536 + aoff);
            }
#pragma unroll
            for (int t = 0; t < 9; ++t) {
                const int dd = t / 3, dc = t % 3;
                const int cur = t & 1;
                if (t < 8) {                  // issue next tap's B loads NOW
                    const int tn = t + 1;
                    const int ddn = tn / 3, dcn = tn % 3;
                    const u16* wb = wt0 + (dcn * 3 + ddn) * 2048;
                    const int nxt = tn & 1;
                    Bh0[nxt] = *(const half8*)(wb + aoff);
                    Bh1[nxt] = *(const half8*)(wb + 512 + aoff);
                    Bl0[nxt] = *(const half8*)(wb + 1024 + aoff);
                    Bl1[nxt] = *(const half8*)(wb + 1536 + aoff);
                }
#pragma unroll
                for (int f = 0; f < 4; ++f) {
                    half8 Ah;
                    if (dd == 0)      Ah = dpp8<0x111>(ax[f + dc]);
                    else if (dd == 1) Ah = ax[f + dc];
                    else              Ah = dpp8<0x101>(ax[f + dc]);
                    acc[f][0] = __builtin_amdgcn_mfma_f32_16x16x32_f16(Ah, Bh0[cur], acc[f][0], 0, 0, 0);
                    acc[f][1] = __builtin_amdgcn_mfma_f32_16x16x32_f16(Ah, Bh1[cur], acc[f][1], 0, 0, 0);
                    acc[f][0] = __builtin_amdgcn_mfma_f32_16x16x32_f16(Ah, Bl0[cur], acc[f][0], 0, 0, 0);
                    acc[f][1] = __builtin_amdgcn_mfma_f32_16x16x32_f16(Ah, Bl1[cur], acc[f][1], 0, 0, 0);
                }
            }
        }
    }

    // ---- epilogue: PReLU, fp16 pack, store to [pos][ch] buffer ----
    const float slope = slopes[sidx];
    u16* Hb = yh + ((size_t)(n * 256) + d1 * 16 + d2) * 8192;
#pragma unroll
    for (int f = 0; f < 4; ++f) {
#pragma unroll
        for (int nf = 0; nf < 2; ++nf) {
            const int o = nf * 16 + l15;
#pragma unroll
            for (int j = 0; j < 4; ++j) {
                float v = acc[f][nf][j];
                v = v >= 0.f ? v : slope * v;
                const int pos = (wv * 4 + f) * 16 + q * 4 + j;
                Hb[pos * 32 + o] = f2h_bits(v);
            }
        }
    }
}

// ---------------------------------------------------------------------------
// Layer 0: IC=2, fp32 math, PReLU; original x layout in, fp16 out.
// ---------------------------------------------------------------------------
__global__ __launch_bounds__(256, 4)
void conv4d_c2(const float* __restrict__ x, const float* __restrict__ wp,
               const float* __restrict__ slopes, u16* __restrict__ yh)
{
    const int blk = blockIdx.x;
    const int d2 = blk & 15, d1 = (blk >> 4) & 15, n = blk >> 8;
    const int tid = threadIdx.x;
    const int c = tid >> 4, d = tid & 15;

    __shared__ float xs[3][3][18][18];
    float* xsf = &xs[0][0][0][0];
    for (int idx = tid; idx < 3 * 3 * 18 * 18; idx += 256) xsf[idx] = 0.0f;

    float acc[32];
#pragma unroll
    for (int o = 0; o < 32; ++o) acc[o] = 0.0f;

    for (int i = 0; i < 2; ++i) {
#pragma unroll
        for (int da = 0; da < 3; ++da) {
            const int a = d1 + da - 1;
#pragma unroll
            for (int db = 0; db < 3; ++db) {
                const int b = d2 + db - 1;
                float v = 0.0f;
                if (a >= 0 && a < L && b >= 0 && b < L)
                    v = x[(((size_t)(n * 2 + i) * L + a) * L + b) * PLANE + c * L + d];
                xs[da][db][c + 1][d + 1] = v;
            }
        }
        __syncthreads();

        const float* wpi = wp + (size_t)i * 81 * 32;
#pragma unroll 1
        for (int da = 0; da < 3; ++da) {
#pragma unroll 1
            for (int db = 0; db < 3; ++db) {
                float xv[3][3];
#pragma unroll
                for (int dc = 0; dc < 3; ++dc)
#pragma unroll
                    for (int dd = 0; dd < 3; ++dd)
                        xv[dc][dd] = xs[da][db][c + dc][d + dd];

                const float* wt = wpi + (da * 3 + db) * 9 * 32;
#pragma unroll
                for (int dc = 0; dc < 3; ++dc) {
#pragma unroll
                    for (int dd = 0; dd < 3; ++dd) {
                        const float* wr = wt + (dc * 3 + dd) * 32;
#pragma unroll
                        for (int o = 0; o < 32; ++o)
                            acc[o] = fmaf(xv[dc][dd], wr[o], acc[o]);
                    }
                }
            }
        }
        __syncthreads();
    }

    const float slope = slopes[0];
    u16* Hb = yh + ((size_t)(n * 256) + d1 * 16 + d2) * 8192 + (size_t)tid * 32;
    short8 hs[4];
#pragma unroll
    for (int k = 0; k < 4; ++k)
#pragma unroll
        for (int j = 0; j < 8; ++j) {
            float v = acc[k * 8 + j];
            v = v >= 0.f ? v : slope * v;
            hs[k][j] = (short)f2h_bits(v);
        }
#pragma unroll
    for (int k = 0; k < 4; ++k)
        *(short8*)(Hb + k * 8) = hs[k];
}

// ---------------------------------------------------------------------------
// Final layer: IC=32, OC=2, no PReLU. fp16 [pos][ch] input, LDS plane
// staging with register prefetch; k5 weights via wave-uniform s_loads.
// ---------------------------------------------------------------------------
__global__ __launch_bounds__(256, 4)
void conv4d_out(const u16* __restrict__ xh, const float* __restrict__ k5,
                float* __restrict__ out)
{
    const int blk = blockIdx.x;
    const int d2 = blk & 15, d1 = (blk >> 4) & 15, n = blk >> 8;
    const int tid = threadIdx.x;
    const int c = tid >> 4, d = tid & 15;

    __shared__ float xs2[32 * 288];   // [ch][18*16]
    for (int i = tid; i < 1024; i += 256) {   // zero rows 0,17 per channel
        int ch = i >> 5, rem = i & 31;
        int rr = (rem >> 4) ? 17 : 0;
        xs2[ch * 288 + rr * 16 + (rem & 15)] = 0.0f;
    }

    const size_t nbase = (size_t)n * 256 * 8192;

    short8 rh[4];
    {
        int a = d1 - 1, b = d2 - 1;
        if (a >= 0 && b >= 0) {
            const u16* Hp = xh + nbase + (size_t)(a * 16 + b) * 8192 + (size_t)tid * 32;
#pragma unroll
            for (int k = 0; k < 4; ++k) rh[k] = *(const short8*)(Hp + k * 8);
        } else {
#pragma unroll
            for (int k = 0; k < 4; ++k) rh[k] = (short8){0,0,0,0,0,0,0,0};
        }
    }

    float acc0 = 0.0f, acc1 = 0.0f;
    const int wpos = (c + 1) * 16 + d;

#pragma unroll 1
    for (int p = 0; p < 9; ++p) {
        __syncthreads();
#pragma unroll
        for (int k = 0; k < 4; ++k)
#pragma unroll
            for (int j = 0; j < 8; ++j)
                xs2[(k * 8 + j) * 288 + wpos] = h2f((u16)rh[k][j]);
        __syncthreads();
        if (p < 8) {
            int pn = p + 1;
            int da = (pn * 11) >> 5, db = pn - da * 3;
            int a = d1 + da - 1, b = d2 + db - 1;
            if (a >= 0 && a < 16 && b >= 0 && b < 16) {
                const u16* Hp = xh + nbase + (size_t)(a * 16 + b) * 8192 + (size_t)tid * 32;
#pragma unroll
                for (int k = 0; k < 4; ++k) rh[k] = *(const short8*)(Hp + k * 8);
            } else {
#pragma unroll
                for (int k = 0; k < 4; ++k) rh[k] = (short8){0,0,0,0,0,0,0,0};
            }
        }

#pragma unroll 1
        for (int dc = 0; dc < 3; ++dc) {
#pragma unroll 1
            for (int dd = 0; dd < 3; ++dd) {
                const int ce = d + dd - 1;
                if ((unsigned)ce < 16u) {         // edge col = pad = 0: skip
                    const int tap = p * 9 + dc * 3 + dd;
                    const int rpos = (c + dc) * 16 + ce;
#pragma unroll
                    for (int i = 0; i < 32; ++i) {
                        const float v = xs2[i * 288 + rpos];
                        acc0 = fmaf(v, k5[i * 81 + tap], acc0);
                        acc1 = fmaf(v, k5[(32 + i) * 81 + tap], acc1);
                    }
                }
            }
        }
    }

    const size_t base = (size_t)(n * 2) * VOL + (size_t)(d1 * 16 + d2) * 256 + tid;
    out[base] = acc0;
    out[base + VOL] = acc1;
}

extern "C" void kernel_launch(void* const* d_in, const int* in_sizes, int n_in,
                              void* d_out, int out_size, void* d_ws, size_t ws_size,
                              hipStream_t stream)
{
    (void)in_sizes; (void)n_in; (void)out_size; (void)ws_size;
    const float* x      = (const float*)d_in[0];
    const float* k0     = (const float*)d_in[1];
    const float* k1     = (const float*)d_in[2];
    const float* k2     = (const float*)d_in[3];
    const float* k3     = (const float*)d_in[4];
    const float* k4     = (const float*)d_in[5];
    const float* k5     = (const float*)d_in[6];
    const float* slopes = (const float*)d_in[7];
    float* outp = (float*)d_out;

    // fp16 activation ping-pong buffers in d_ws: 33.5 MB each.
    u16* b0 = (u16*)d_ws;
    u16* b1 = b0 + (size_t)2048 * 8192;

    // Scratch weights in d_out (overwritten by the final conv):
    u16* wpk = (u16*)d_out;                 // 663552 u16 = 1.33 MB
    float* wp0 = outp + 331776;             // 5184 fp32 after that

    pack_half<<<dim3(1296), 256, 0, stream>>>(k1, k2, k3, k4, wpk);
    pack_w0<<<dim3(21), 256, 0, stream>>>(k0, wp0);

    const dim3 grid(8 * L * L);
    const dim3 block(256);

    conv4d_c2<<<grid, block, 0, stream>>>(x, wp0, slopes, b0);
    conv4d_mfma<<<grid, block, 0, stream>>>(b0, wpk + (size_t)0 * 81 * 2048, slopes, 1, b1);
    conv4d_mfma<<<grid, block, 0, stream>>>(b1, wpk + (size_t)1 * 81 * 2048, slopes, 2, b0);
    conv4d_mfma<<<grid, block, 0, stream>>>(b0, wpk + (size_t)2 * 81 * 2048, slopes, 3, b1);
    conv4d_mfma<<<grid, block, 0, stream>>>(b1, wpk + (size_t)3 * 81 * 2048, slopes, 4, b0);
    conv4d_out<<<grid, block, 0, stream>>>(b0, k5, outp);
}